// Round 7
// baseline (59.504 us; speedup 1.0000x reference)
//
#include <hip/hip_runtime.h>

// x: (B=8, C=64, H=56, W=56) fp32; out: (B,C,49,3136) fp32
// out[b,c,(i*7+j),h*56+w] = x[b,c,h,w] - x[b,c, refl(h+i-3), refl(w+j-3)]
#define HH 56
#define WW 56
#define HWOUT (HH * WW)          // 3136 elements = 12544 B per image
#define NBC (8 * 64)             // 512 images; one block per image

typedef float f32x4 __attribute__((ext_vector_type(4)));

// Single-bounce reflection, valid for t in [-3, 58]
__device__ __forceinline__ int refl(int t) {
    t = (t < 0) ? -t : t;
    return (t >= HH) ? (2 * HH - 2 - t) : t;
}

__global__ __launch_bounds__(256) void sub_kernel(const float* __restrict__ x,
                                                  float* __restrict__ out) {
    __shared__ float img[HWOUT];             // 12544 B, read-only after barrier
    const int bc = blockIdx.x;
    const int tid = threadIdx.x;

    // Stage the whole image into LDS with one coalesced pass (the ONLY global
    // reads in the kernel -> chip-wide FETCH ~= 6.4 MB minimum).
    const float* __restrict__ gimg = x + (size_t)bc * HWOUT;
    for (int q = tid; q < HWOUT / 4; q += 256) {
        *reinterpret_cast<f32x4*>(&img[q * 4]) =
            *reinterpret_cast<const f32x4*>(gimg + q * 4);
    }
    __syncthreads();

    float* __restrict__ obase = out + (size_t)bc * 49 * HWOUT;  // 614 KB contiguous per block

    for (int di = 0; di < 7; ++di) {
        float* __restrict__ oplane0 = obase + (size_t)di * 7 * HWOUT;
        for (int q = tid; q < HWOUT / 4; q += 256) {
            const int e = q * 4;             // 16B-aligned element offset
            const int h = e / WW;
            const int w = e - h * WW;        // 0,4,...,52

            const float* crow = &img[h * WW];                    // row stride 224B (16B-mult)
            const float* nrow = &img[refl(h + di - 3) * WW];

            const f32x4 cen = *reinterpret_cast<const f32x4*>(crow + w);
            const f32x4 lo  = *reinterpret_cast<const f32x4*>(nrow + (w == 0  ? 0  : w - 4));
            const f32x4 mid = *reinterpret_cast<const f32x4*>(nrow + w);
            const f32x4 hi  = *reinterpret_cast<const f32x4*>(nrow + (w == 52 ? 48 : w + 4));

            // wnd[idx] = nrow[w-4+idx] after reflection; idx 1..10 used.
            float wnd[12];
            wnd[0] = lo.x;  wnd[1] = lo.y;  wnd[2] = lo.z;  wnd[3] = lo.w;
            wnd[4] = mid.x; wnd[5] = mid.y; wnd[6] = mid.z; wnd[7] = mid.w;
            wnd[8] = hi.x;  wnd[9] = hi.y;  wnd[10] = hi.z; wnd[11] = hi.w;
            // Register-only edge fixups (reflected values already live in mid):
            if (w == 0)  { wnd[1] = mid.w; wnd[2] = mid.z; wnd[3] = mid.y; }
            if (w == 52) { wnd[8] = mid.z; wnd[9] = mid.y; wnd[10] = mid.x; }

            float* op = oplane0 + e;
            #pragma unroll
            for (int djj = 0; djj < 7; ++djj) {   // dj = djj-3; static wnd indices
                f32x4 r;
                r.x = cen.x - wnd[djj + 1];
                r.y = cen.y - wnd[djj + 2];
                r.z = cen.z - wnd[djj + 3];
                r.w = cen.w - wnd[djj + 4];
                *reinterpret_cast<f32x4*>(op + (size_t)djj * HWOUT) = r;
            }
        }
    }
}

extern "C" void kernel_launch(void* const* d_in, const int* in_sizes, int n_in,
                              void* d_out, int out_size, void* d_ws, size_t ws_size,
                              hipStream_t stream) {
    const float* x = (const float*)d_in[0];
    float* out = (float*)d_out;
    sub_kernel<<<dim3(NBC), dim3(256), 0, stream>>>(x, out);
}

// Round 8
// 58.456 us; speedup vs baseline: 1.0179x; 1.0179x over previous
//
#include <hip/hip_runtime.h>

// x: (B=8, C=64, H=56, W=56) fp32; out: (B,C,49,3136) fp32
// out[b,c,(i*7+j),h*56+w] = x[b,c,h,w] - x[b,c, refl(h+i-3), refl(w+j-3)]
#define HH 56
#define WW 56
#define HWOUT (HH * WW)          // 3136 elements = 12544 B per image
#define NBC (8 * 64)             // 512 images; one block per image
#define NQ (HWOUT / 4)           // 784 f32x4 chunks per plane

typedef float f32x4 __attribute__((ext_vector_type(4)));

// Single-bounce reflection, valid for t in [-3, 58]
__device__ __forceinline__ int refl(int t) {
    t = (t < 0) ? -t : t;
    return (t >= HH) ? (2 * HH - 2 - t) : t;
}

__global__ __launch_bounds__(256) void sub_kernel(const float* __restrict__ x,
                                                  float* __restrict__ out) {
    __shared__ float img[HWOUT];             // 12544 B, read-only after barrier
    const int bc = blockIdx.x;
    const int tid = threadIdx.x;

    const float* __restrict__ gimg = x + (size_t)bc * HWOUT;
    for (int q = tid; q < NQ; q += 256) {
        *reinterpret_cast<f32x4*>(&img[q * 4]) =
            *reinterpret_cast<const f32x4*>(gimg + q * 4);
    }
    __syncthreads();

    // Thread owns chunks q_k = tid + 256k (k=0..2 always; k=3 only tid<16).
    const bool tail = tid < (NQ - 768);      // 16 threads

    int h[4], w[4];
    f32x4 cen[4];
    #pragma unroll
    for (int k = 0; k < 4; ++k) {
        const int q = (k < 3 || tail) ? (tid + 256 * k) : tid;  // safe dummy for dead lane
        const int e = q * 4;
        h[k] = e / WW;
        w[k] = e - h[k] * WW;                // 0,4,...,52
        cen[k] = *reinterpret_cast<const f32x4*>(&img[h[k] * WW + w[k]]);  // di/dj-invariant
    }

    float* __restrict__ obase = out + (size_t)bc * 49 * HWOUT;

    for (int di = 0; di < 7; ++di) {
        // Neighbor-row windows for all 4 chunks, kept in registers across dj.
        // wnd[k][idx] = nrow[w-4+idx] after reflection; idx 1..10 used. All
        // indices static after unroll (no scratch spill).
        float wnd[4][12];
        #pragma unroll
        for (int k = 0; k < 4; ++k) {
            const float* nrow = &img[refl(h[k] + di - 3) * WW];
            const f32x4 lo  = *reinterpret_cast<const f32x4*>(nrow + (w[k] == 0  ? 0  : w[k] - 4));
            const f32x4 mid = *reinterpret_cast<const f32x4*>(nrow + w[k]);
            const f32x4 hi  = *reinterpret_cast<const f32x4*>(nrow + (w[k] == 52 ? 48 : w[k] + 4));
            wnd[k][0] = lo.x;  wnd[k][1] = lo.y;  wnd[k][2]  = lo.z;  wnd[k][3]  = lo.w;
            wnd[k][4] = mid.x; wnd[k][5] = mid.y; wnd[k][6]  = mid.z; wnd[k][7]  = mid.w;
            wnd[k][8] = hi.x;  wnd[k][9] = hi.y;  wnd[k][10] = hi.z;  wnd[k][11] = hi.w;
            // Register-only reflection fixups (values already live in mid):
            if (w[k] == 0)  { wnd[k][1] = mid.w; wnd[k][2] = mid.z; wnd[k][3]  = mid.y; }
            if (w[k] == 52) { wnd[k][8] = mid.z; wnd[k][9] = mid.y; wnd[k][10] = mid.x; }
        }

        float* __restrict__ oplane = obase + (size_t)di * 7 * HWOUT;
        // PLANE-MAJOR stores: finish each 12.5 KB plane contiguously before
        // the next -> one active write region per block (fill-like stream).
        #pragma unroll
        for (int djj = 0; djj < 7; ++djj) {
            float* __restrict__ op = oplane + (size_t)djj * HWOUT;
            #pragma unroll
            for (int k = 0; k < 4; ++k) {
                if (k < 3 || tail) {
                    f32x4 r;
                    r.x = cen[k].x - wnd[k][djj + 1];
                    r.y = cen[k].y - wnd[k][djj + 2];
                    r.z = cen[k].z - wnd[k][djj + 3];
                    r.w = cen[k].w - wnd[k][djj + 4];
                    *reinterpret_cast<f32x4*>(op + (size_t)(tid + 256 * k) * 4) = r;
                }
            }
        }
    }
}

extern "C" void kernel_launch(void* const* d_in, const int* in_sizes, int n_in,
                              void* d_out, int out_size, void* d_ws, size_t ws_size,
                              hipStream_t stream) {
    const float* x = (const float*)d_in[0];
    float* out = (float*)d_out;
    sub_kernel<<<dim3(NBC), dim3(256), 0, stream>>>(x, out);
}

// Round 9
// 57.047 us; speedup vs baseline: 1.0431x; 1.0247x over previous
//
#include <hip/hip_runtime.h>

// x: (B=8, C=64, H=56, W=56) fp32; out: (B,C,49,3136) fp32
// out[b,c,(i*7+j),h*56+w] = x[b,c,h,w] - x[b,c, refl(h+i-3), refl(w+j-3)]
#define HH 56
#define WW 56
#define HWOUT (HH * WW)          // 3136 elements = 12544 B per image
#define NBLK (8 * 64 * 7)        // block = (bc, di)
#define NQ (HWOUT / 4)           // 784 f32x4 chunks per plane

typedef float f32x4 __attribute__((ext_vector_type(4)));

// Single-bounce reflection, valid for t in [-3, 58]
__device__ __forceinline__ int refl(int t) {
    t = (t < 0) ? -t : t;
    return (t >= HH) ? (2 * HH - 2 - t) : t;
}

__global__ __launch_bounds__(256) void sub_kernel(const float* __restrict__ x,
                                                  float* __restrict__ out) {
    const int blk = blockIdx.x;
    const int di = blk % 7;
    const int bc = blk / 7;
    const int tid = threadIdx.x;

    const float* __restrict__ img = x + (size_t)bc * HWOUT;
    float* __restrict__ oplane0 = out + ((size_t)bc * 49 + (size_t)di * 7) * HWOUT;

    const bool tail = tid < (NQ - 768);      // 16 threads own a 4th chunk

    // ---- Phase 1: issue ALL loads (16 vector loads / thread), no stores ----
    int w[4];
    f32x4 cen[4], lo[4], mid[4], hi[4];
    #pragma unroll
    for (int k = 0; k < 4; ++k) {
        const int q = (k < 3 || tail) ? (tid + 256 * k) : tid;  // dead-lane dummy
        const int e = q * 4;
        const int h = e / WW;
        w[k] = e - h * WW;                   // 0,4,...,52
        const float* crow = img + h * WW;
        const float* nrow = img + refl(h + di - 3) * WW;
        cen[k] = *reinterpret_cast<const f32x4*>(crow + w[k]);
        lo[k]  = *reinterpret_cast<const f32x4*>(nrow + (w[k] == 0  ? 0  : w[k] - 4));
        mid[k] = *reinterpret_cast<const f32x4*>(nrow + w[k]);
        hi[k]  = *reinterpret_cast<const f32x4*>(nrow + (w[k] == 52 ? 48 : w[k] + 4));
    }

    // ---- Phase 2: one wait, then an uninterrupted 28-store burst ----
    // (compiler emits a single s_waitcnt vmcnt(0) before the first use;
    //  everything after is VALU + stores, no further waits)
    #pragma unroll
    for (int k = 0; k < 4; ++k) {
        if (k == 3 && !tail) break;
        // wnd[idx] = nrow[w-4+idx] after reflection; idx 1..10 used; static after unroll.
        float wnd[12];
        wnd[0] = lo[k].x;  wnd[1] = lo[k].y;  wnd[2]  = lo[k].z;  wnd[3]  = lo[k].w;
        wnd[4] = mid[k].x; wnd[5] = mid[k].y; wnd[6]  = mid[k].z; wnd[7]  = mid[k].w;
        wnd[8] = hi[k].x;  wnd[9] = hi[k].y;  wnd[10] = hi[k].z;  wnd[11] = hi[k].w;
        if (w[k] == 0)  { wnd[1] = mid[k].w; wnd[2] = mid[k].z; wnd[3]  = mid[k].y; }
        if (w[k] == 52) { wnd[8] = mid[k].z; wnd[9] = mid[k].y; wnd[10] = mid[k].x; }

        float* __restrict__ op = oplane0 + (size_t)(tid + 256 * k) * 4;
        #pragma unroll
        for (int djj = 0; djj < 7; ++djj) {
            f32x4 r;
            r.x = cen[k].x - wnd[djj + 1];
            r.y = cen[k].y - wnd[djj + 2];
            r.z = cen[k].z - wnd[djj + 3];
            r.w = cen[k].w - wnd[djj + 4];
            *reinterpret_cast<f32x4*>(op + (size_t)djj * HWOUT) = r;
        }
    }
}

extern "C" void kernel_launch(void* const* d_in, const int* in_sizes, int n_in,
                              void* d_out, int out_size, void* d_ws, size_t ws_size,
                              hipStream_t stream) {
    const float* x = (const float*)d_in[0];
    float* out = (float*)d_out;
    sub_kernel<<<dim3(NBLK), dim3(256), 0, stream>>>(x, out);
}